// Round 1
// baseline (224.894 us; speedup 1.0000x reference)
//
#include <hip/hip_runtime.h>

typedef _Float16 f16;
typedef _Float16 f16x8 __attribute__((ext_vector_type(8)));
typedef _Float16 f16x4 __attribute__((ext_vector_type(4)));
typedef float f32x4 __attribute__((ext_vector_type(4)));

#define MFMA16(a, b, c) __builtin_amdgcn_mfma_f32_16x16x32_f16((a), (b), (c), 0, 0, 0)

// ---------------- fp32 -> f16 convert ----------------
__global__ void cvt_f32_f16(const float* __restrict__ s, f16* __restrict__ d, int n) {
    int i = (blockIdx.x * 256 + threadIdx.x) * 4;
    if (i < n) {
        float4 v = *(const float4*)(s + i);
        f16x4 o = {(f16)v.x, (f16)v.y, (f16)v.z, (f16)v.w};
        *(f16x4*)(d + i) = o;
    }
}

// ---------------- NT GEMM: C[m][n] = sum_k A[m][k] * W[n][k] (+bias epilogues) ----
// A: [M][512] f16 row-major, W: [N][512] f16 row-major. Tile 64x64, BK=32, 4 waves.
// MODE 0: qkv epilogue (scale q, split q/k/v, v transposed). MODE 1: fp32 out + bias.
template<int MODE>
__global__ __launch_bounds__(256) void gemm_nt(const f16* __restrict__ A, const f16* __restrict__ W,
                                               const float* __restrict__ bias, float* __restrict__ Cf,
                                               f16* __restrict__ Qb, f16* __restrict__ Kb,
                                               f16* __restrict__ Vt) {
    __shared__ f16 As[64][40];  // 32 + 8 pad (row stride 80B, 16B aligned, banks spread)
    __shared__ f16 Bs[64][40];
    const int m0 = blockIdx.x * 64, n0 = blockIdx.y * 64;
    const int tid = threadIdx.x;
    const int w = tid >> 6, l = tid & 63;
    const int wm = w >> 1, wn = w & 1;
    const int lr = l & 15, lg = l >> 4;
    const int srow = tid >> 2, scol = (tid & 3) * 8;
    const f16* ag = A + (size_t)(m0 + srow) * 512 + scol;
    const f16* bg = W + (size_t)(n0 + srow) * 512 + scol;
    f32x4 acc[2][2] = {};
    for (int k0 = 0; k0 < 512; k0 += 32) {
        *(f16x8*)&As[srow][scol] = *(const f16x8*)(ag + k0);
        *(f16x8*)&Bs[srow][scol] = *(const f16x8*)(bg + k0);
        __syncthreads();
        f16x8 af[2], bf[2];
#pragma unroll
        for (int mf = 0; mf < 2; ++mf) af[mf] = *(f16x8*)&As[32 * wm + 16 * mf + lr][8 * lg];
#pragma unroll
        for (int nf = 0; nf < 2; ++nf) bf[nf] = *(f16x8*)&Bs[32 * wn + 16 * nf + lr][8 * lg];
#pragma unroll
        for (int mf = 0; mf < 2; ++mf)
#pragma unroll
            for (int nf = 0; nf < 2; ++nf) acc[mf][nf] = MFMA16(af[mf], bf[nf], acc[mf][nf]);
        __syncthreads();
    }
#pragma unroll
    for (int mf = 0; mf < 2; ++mf)
#pragma unroll
        for (int nf = 0; nf < 2; ++nf)
#pragma unroll
            for (int r = 0; r < 4; ++r) {
                int rr = 32 * wm + 16 * mf + 4 * lg + r;
                int cc = 32 * wn + 16 * nf + lr;
                int m = m0 + rr, e = n0 + cc;
                float val = acc[mf][nf][r] + bias[e];
                if (MODE == 0) {
                    int bb = m >> 11, s = m & 2047;
                    if (e < 512)
                        Qb[((size_t)bb * 2048 + s) * 512 + e] = (f16)(val * 0.04419417382415922f);
                    else if (e < 1024)
                        Kb[((size_t)bb * 2048 + s) * 512 + (e - 512)] = (f16)val;
                    else
                        Vt[((size_t)bb * 512 + (e - 1024)) * 2048 + s] = (f16)val;
                } else {
                    Cf[(size_t)m * 512 + e] = val;
                }
            }
}

// ---------------- flash attention ----------------
// Per WG: one (batch, 32-q-row block). 4 waves; wave w owns d-cols [128w, 128w+128).
// Online softmax state per q-row; K/V streamed from global (L2), Q + S + P in LDS.
__global__ __launch_bounds__(256) void flash_attn(const f16* __restrict__ Qb, const f16* __restrict__ Kb,
                                                  const f16* __restrict__ Vt, f16* __restrict__ AO) {
    __shared__ f16 Qs[32][520];    // 512 + 8 pad
    __shared__ float Ss[32][68];   // 64 + 4 pad (f32 scores)
    __shared__ f16 Ps[32][72];     // 64 + 8 pad (exp'd probs, f16)
    __shared__ float alpha_s[32];
    __shared__ float lsum_s[32];
    const int b = blockIdx.x >> 6;
    const int q0 = (blockIdx.x & 63) * 32;
    const int tid = threadIdx.x, w = tid >> 6, l = tid & 63;
    const int lr = l & 15, lg = l >> 4;
    const int srow = l & 31, sh = l >> 5;
    const f16* Qg = Qb + ((size_t)b * 2048 + q0) * 512;
    const f16* Kg = Kb + (size_t)b * 2048 * 512;
    const f16* Vg = Vt + (size_t)b * 512 * 2048;
    for (int i = tid; i < 2048; i += 256) {
        int r = i >> 6, c = (i & 63) * 8;
        *(f16x8*)&Qs[r][c] = *(const f16x8*)&Qg[(size_t)r * 512 + c];
    }
    f32x4 acc[2][8] = {};
    float m_st = -1e30f, l_st = 0.f;
    __syncthreads();
    for (int kt = 0; kt < 32; ++kt) {
        const int key0 = kt * 64;
        // --- phase A: scores S[0:32][16w:16w+16] = Q . K^T ---
        f32x4 sacc0 = {0.f, 0.f, 0.f, 0.f}, sacc1 = {0.f, 0.f, 0.f, 0.f};
        const f16* kp = Kg + (size_t)(key0 + 16 * w + lr) * 512 + 8 * lg;
#pragma unroll
        for (int kd = 0; kd < 16; ++kd) {
            f16x8 bfr = *(const f16x8*)(kp + kd * 32);
            f16x8 a0 = *(f16x8*)&Qs[lr][kd * 32 + 8 * lg];
            f16x8 a1 = *(f16x8*)&Qs[lr + 16][kd * 32 + 8 * lg];
            sacc0 = MFMA16(a0, bfr, sacc0);
            sacc1 = MFMA16(a1, bfr, sacc1);
        }
#pragma unroll
        for (int r = 0; r < 4; ++r) {
            Ss[4 * lg + r][16 * w + lr] = sacc0[r];
            Ss[16 + 4 * lg + r][16 * w + lr] = sacc1[r];
        }
        __syncthreads();
        // --- phase B: online softmax (each wave redundantly; lane -> row l&31, half sh) ---
        float4 sv[8];
#pragma unroll
        for (int j = 0; j < 8; ++j) sv[j] = *(float4*)&Ss[srow][32 * sh + 4 * j];
        float mt = -1e30f;
#pragma unroll
        for (int j = 0; j < 8; ++j)
            mt = fmaxf(mt, fmaxf(fmaxf(sv[j].x, sv[j].y), fmaxf(sv[j].z, sv[j].w)));
        mt = fmaxf(mt, __shfl_xor(mt, 32));
        float mnew = fmaxf(m_st, mt);
        float alpha = __expf(m_st - mnew);
        float ps = 0.f;
#pragma unroll
        for (int j = 0; j < 8; ++j) {
            float e0 = __expf(sv[j].x - mnew), e1 = __expf(sv[j].y - mnew);
            float e2 = __expf(sv[j].z - mnew), e3 = __expf(sv[j].w - mnew);
            ps += (e0 + e1) + (e2 + e3);
            f16x4 pv = {(f16)e0, (f16)e1, (f16)e2, (f16)e3};
            *(f16x4*)&Ps[srow][32 * sh + 4 * j] = pv;
        }
        ps += __shfl_xor(ps, 32);
        l_st = l_st * alpha + ps;
        m_st = mnew;
        if (l < 32) alpha_s[l] = alpha;
        __syncthreads();
        // --- phase C: rescale O, then O += P . V ---
        float ar0[4], ar1[4];
#pragma unroll
        for (int r = 0; r < 4; ++r) {
            ar0[r] = alpha_s[4 * lg + r];
            ar1[r] = alpha_s[16 + 4 * lg + r];
        }
#pragma unroll
        for (int nf = 0; nf < 8; ++nf)
#pragma unroll
            for (int r = 0; r < 4; ++r) {
                acc[0][nf][r] *= ar0[r];
                acc[1][nf][r] *= ar1[r];
            }
        f16x8 pa[2][2];
#pragma unroll
        for (int mf = 0; mf < 2; ++mf)
#pragma unroll
            for (int ks = 0; ks < 2; ++ks)
                pa[mf][ks] = *(f16x8*)&Ps[lr + 16 * mf][32 * ks + 8 * lg];
        const f16* vp = Vg + (size_t)(128 * w + lr) * 2048 + key0 + 8 * lg;
#pragma unroll
        for (int nf = 0; nf < 8; ++nf) {
            f16x8 vb0 = *(const f16x8*)(vp + (size_t)nf * 16 * 2048);
            f16x8 vb1 = *(const f16x8*)(vp + (size_t)nf * 16 * 2048 + 32);
            acc[0][nf] = MFMA16(pa[0][0], vb0, acc[0][nf]);
            acc[1][nf] = MFMA16(pa[1][0], vb0, acc[1][nf]);
            acc[0][nf] = MFMA16(pa[0][1], vb1, acc[0][nf]);
            acc[1][nf] = MFMA16(pa[1][1], vb1, acc[1][nf]);
        }
        // no barrier needed: next phase A only writes Ss (readers done pre-barrier2);
        // next phase B (Ps/alpha writes) is behind next iteration's barrier1.
    }
    if (l < 32) lsum_s[l] = l_st;
    __syncthreads();
    f16* aop = AO + ((size_t)b * 2048 + q0) * 512 + 128 * w;
#pragma unroll
    for (int mf = 0; mf < 2; ++mf)
#pragma unroll
        for (int r = 0; r < 4; ++r) {
            int rr = 16 * mf + 4 * lg + r;
            float inv = 1.f / lsum_s[rr];
#pragma unroll
            for (int nf = 0; nf < 8; ++nf)
                aop[(size_t)rr * 512 + 16 * nf + lr] = (f16)(acc[mf][nf][r] * inv);
        }
}

// ---------------- launch ----------------
extern "C" void kernel_launch(void* const* d_in, const int* in_sizes, int n_in,
                              void* d_out, int out_size, void* d_ws, size_t ws_size,
                              hipStream_t stream) {
    (void)in_sizes; (void)n_in; (void)out_size; (void)ws_size;
    const float* x = (const float*)d_in[0];
    const float* qkv_w = (const float*)d_in[1];
    const float* qkv_b = (const float*)d_in[2];
    const float* out_w = (const float*)d_in[3];
    const float* out_b = (const float*)d_in[4];
    char* ws = (char*)d_ws;
    f16* xh    = (f16*)(ws + 0);         // 8192*512*2      = 8,388,608
    f16* wqkvh = (f16*)(ws + 8388608);   // 1536*512*2      = 1,572,864
    f16* wouth = (f16*)(ws + 9961472);   // 512*512*2       =   524,288
    f16* Qb    = (f16*)(ws + 10485760);  // 4*2048*512*2    = 8,388,608 (pre-scaled)
    f16* Kb    = (f16*)(ws + 18874368);  // 8,388,608
    f16* Vt    = (f16*)(ws + 27262976);  // [b][d][s] transposed, 8,388,608
    f16* AO    = (f16*)(ws + 35651584);  // attention out f16, 8,388,608

    cvt_f32_f16<<<4096, 256, 0, stream>>>(x, xh, 4194304);
    cvt_f32_f16<<<768, 256, 0, stream>>>(qkv_w, wqkvh, 786432);
    cvt_f32_f16<<<256, 256, 0, stream>>>(out_w, wouth, 262144);

    gemm_nt<0><<<dim3(128, 24), 256, 0, stream>>>(xh, wqkvh, qkv_b, nullptr, Qb, Kb, Vt);

    flash_attn<<<256, 256, 0, stream>>>(Qb, Kb, Vt, AO);

    gemm_nt<1><<<dim3(128, 8), 256, 0, stream>>>(AO, wouth, out_b, (float*)d_out,
                                                 nullptr, nullptr, nullptr);
}

// Round 2
// 202.615 us; speedup vs baseline: 1.1100x; 1.1100x over previous
//
#include <hip/hip_runtime.h>

typedef _Float16 f16;
typedef _Float16 f16x8 __attribute__((ext_vector_type(8)));
typedef _Float16 f16x4 __attribute__((ext_vector_type(4)));
typedef float f32x4 __attribute__((ext_vector_type(4)));

#define MFMA16(a, b, c) __builtin_amdgcn_mfma_f32_16x16x32_f16((a), (b), (c), 0, 0, 0)

// ---------------- fp32 -> f16 convert ----------------
__global__ void cvt_f32_f16(const float* __restrict__ s, f16* __restrict__ d, int n) {
    int i = (blockIdx.x * 256 + threadIdx.x) * 4;
    if (i < n) {
        float4 v = *(const float4*)(s + i);
        f16x4 o = {(f16)v.x, (f16)v.y, (f16)v.z, (f16)v.w};
        *(f16x4*)(d + i) = o;
    }
}

// ---------------- NT GEMM: C[m][n] = sum_k A[m][k] * W[n][k] (+bias epilogues) ----
template<int MODE>
__global__ __launch_bounds__(256) void gemm_nt(const f16* __restrict__ A, const f16* __restrict__ W,
                                               const float* __restrict__ bias, float* __restrict__ Cf,
                                               f16* __restrict__ Qb, f16* __restrict__ Kb,
                                               f16* __restrict__ Vt) {
    __shared__ f16 As[64][40];
    __shared__ f16 Bs[64][40];
    const int m0 = blockIdx.x * 64, n0 = blockIdx.y * 64;
    const int tid = threadIdx.x;
    const int w = tid >> 6, l = tid & 63;
    const int wm = w >> 1, wn = w & 1;
    const int lr = l & 15, lg = l >> 4;
    const int srow = tid >> 2, scol = (tid & 3) * 8;
    const f16* ag = A + (size_t)(m0 + srow) * 512 + scol;
    const f16* bg = W + (size_t)(n0 + srow) * 512 + scol;
    f32x4 acc[2][2] = {};
    for (int k0 = 0; k0 < 512; k0 += 32) {
        *(f16x8*)&As[srow][scol] = *(const f16x8*)(ag + k0);
        *(f16x8*)&Bs[srow][scol] = *(const f16x8*)(bg + k0);
        __syncthreads();
        f16x8 af[2], bf[2];
#pragma unroll
        for (int mf = 0; mf < 2; ++mf) af[mf] = *(f16x8*)&As[32 * wm + 16 * mf + lr][8 * lg];
#pragma unroll
        for (int nf = 0; nf < 2; ++nf) bf[nf] = *(f16x8*)&Bs[32 * wn + 16 * nf + lr][8 * lg];
#pragma unroll
        for (int mf = 0; mf < 2; ++mf)
#pragma unroll
            for (int nf = 0; nf < 2; ++nf) acc[mf][nf] = MFMA16(af[mf], bf[nf], acc[mf][nf]);
        __syncthreads();
    }
#pragma unroll
    for (int mf = 0; mf < 2; ++mf)
#pragma unroll
        for (int nf = 0; nf < 2; ++nf)
#pragma unroll
            for (int r = 0; r < 4; ++r) {
                int rr = 32 * wm + 16 * mf + 4 * lg + r;
                int cc = 32 * wn + 16 * nf + lr;
                int m = m0 + rr, e = n0 + cc;
                float val = acc[mf][nf][r] + bias[e];
                if (MODE == 0) {
                    int bb = m >> 11, s = m & 2047;
                    if (e < 512)
                        Qb[((size_t)bb * 2048 + s) * 512 + e] = (f16)(val * 0.04419417382415922f);
                    else if (e < 1024)
                        Kb[((size_t)bb * 2048 + s) * 512 + (e - 512)] = (f16)val;
                    else
                        Vt[((size_t)bb * 512 + (e - 1024)) * 2048 + s] = (f16)val;
                } else {
                    Cf[(size_t)m * 512 + e] = val;
                }
            }
}

// ---------------- flash attention, split-K over key chunks ----------------
// Grid: 4 batches * 64 qblocks * NSPLIT, remapped so batch b lives on XCDs {2b,2b+1}.
// 4 waves; wave w owns d-cols [128w,128w+128) for PV and keys [16w,16w+16) for QK^T.
// Scores S and probs P alias one f16 LDS buffer (softmax is in-place, per-wave 8-row bands).
template<int NSPLIT, bool PART>
__global__ __launch_bounds__(256, 4) void flash_attn(const f16* __restrict__ Qb, const f16* __restrict__ Kb,
                                                     const f16* __restrict__ Vt, f16* __restrict__ AO,
                                                     f16* __restrict__ Opart, float* __restrict__ Ml) {
    __shared__ f16 Qs[32 * 512];   // XOR-swizzled on 16B chunks: c' = c ^ (row&7)
    __shared__ f16 SP[32 * 64];    // scores then probs, aliased, swizzled same way
    __shared__ float alpha_s[32];
    __shared__ float lsum_s[32];
    const int bid = blockIdx.x;
    const int xcd = bid & 7, slot = bid >> 3;
    const int b = xcd >> 1;
    const int t = slot * 2 + (xcd & 1);      // 0 .. 64*NSPLIT-1
    const int q0 = (t / NSPLIT) * 32;
    const int ks = t % NSPLIT;
    const int kbase = ks * (2048 / NSPLIT);
    const int nkt = 32 / NSPLIT;
    const int tid = threadIdx.x, w = tid >> 6, l = tid & 63;
    const int lr = l & 15, lg = l >> 4;
    const int srow8 = 8 * w + (l & 7);       // softmax row owned by this lane
    const int g = l >> 3;                    // softmax col-group 0..7
    const f16* Qg = Qb + ((size_t)b * 2048 + q0) * 512;
    const f16* Kg = Kb + (size_t)b * 2048 * 512;
    const f16* Vg = Vt + (size_t)b * 512 * 2048;
    for (int i = tid; i < 2048; i += 256) {
        int r = i >> 6, c16 = i & 63;
        *(f16x8*)&Qs[r * 512 + ((c16 ^ (r & 7)) * 8)] = *(const f16x8*)&Qg[(size_t)r * 512 + c16 * 8];
    }
    f32x4 acc[2][8] = {};
    float m_st = -1e30f, l_st = 0.f;
    __syncthreads();
    for (int kt = 0; kt < nkt; ++kt) {
        const int key0 = kbase + kt * 64;
        // --- phase A: S[0:32][16w..16w+16] = Q . K^T, 4 sub-acc chains ---
        f32x4 sa0 = {}, sa1 = {}, sb0 = {}, sb1 = {};
        const f16* kp = Kg + (size_t)(key0 + 16 * w + lr) * 512 + 8 * lg;
#pragma unroll
        for (int kd = 0; kd < 16; kd += 2) {
            f16x8 bf0 = *(const f16x8*)(kp + kd * 32);
            f16x8 bf1 = *(const f16x8*)(kp + kd * 32 + 32);
            int c0 = 4 * kd + lg, c1 = 4 * kd + 4 + lg;
            f16x8 a00 = *(f16x8*)&Qs[lr * 512 + ((c0 ^ (lr & 7)) * 8)];
            f16x8 a10 = *(f16x8*)&Qs[(lr + 16) * 512 + ((c0 ^ (lr & 7)) * 8)];
            f16x8 a01 = *(f16x8*)&Qs[lr * 512 + ((c1 ^ (lr & 7)) * 8)];
            f16x8 a11 = *(f16x8*)&Qs[(lr + 16) * 512 + ((c1 ^ (lr & 7)) * 8)];
            sa0 = MFMA16(a00, bf0, sa0);
            sa1 = MFMA16(a10, bf0, sa1);
            sb0 = MFMA16(a01, bf1, sb0);
            sb1 = MFMA16(a11, bf1, sb1);
        }
        sa0 += sb0;
        sa1 += sb1;
        {
            const int col = 16 * w + lr;
            const int ch = col >> 3, cl = col & 7;
#pragma unroll
            for (int r = 0; r < 4; ++r) {
                int r0 = 4 * lg + r, r1 = 16 + 4 * lg + r;
                SP[r0 * 64 + ((ch ^ (r0 & 7)) * 8) + cl] = (f16)sa0[r];
                SP[r1 * 64 + ((ch ^ (r1 & 7)) * 8) + cl] = (f16)sa1[r];
            }
        }
        __syncthreads();
        // --- phase B: in-place softmax; wave w owns rows [8w, 8w+8) ---
        {
            f16* sp = &SP[srow8 * 64 + ((g ^ (srow8 & 7)) * 8)];
            f16x8 sv = *(f16x8*)sp;
            float s[8];
#pragma unroll
            for (int j = 0; j < 8; ++j) s[j] = (float)sv[j];
            float mt = fmaxf(fmaxf(fmaxf(s[0], s[1]), fmaxf(s[2], s[3])),
                             fmaxf(fmaxf(s[4], s[5]), fmaxf(s[6], s[7])));
            mt = fmaxf(mt, __shfl_xor(mt, 8));
            mt = fmaxf(mt, __shfl_xor(mt, 16));
            mt = fmaxf(mt, __shfl_xor(mt, 32));
            float mnew = fmaxf(m_st, mt);
            float alpha = __expf(m_st - mnew);
            float ps = 0.f;
            f16x8 pv;
#pragma unroll
            for (int j = 0; j < 8; ++j) {
                float e = __expf(s[j] - mnew);
                ps += e;
                pv[j] = (f16)e;
            }
            *(f16x8*)sp = pv;
            ps += __shfl_xor(ps, 8);
            ps += __shfl_xor(ps, 16);
            ps += __shfl_xor(ps, 32);
            l_st = l_st * alpha + ps;
            m_st = mnew;
            if (g == 0) alpha_s[srow8] = alpha;
        }
        __syncthreads();
        // --- phase C: read P fragments + alpha, then rescale & PV MFMA ---
        f16x8 pa[2][2];
#pragma unroll
        for (int mf = 0; mf < 2; ++mf)
#pragma unroll
            for (int kk = 0; kk < 2; ++kk) {
                int r = lr + 16 * mf, c = 4 * kk + lg;
                pa[mf][kk] = *(f16x8*)&SP[r * 64 + ((c ^ (r & 7)) * 8)];
            }
        float ar0[4], ar1[4];
#pragma unroll
        for (int r = 0; r < 4; ++r) {
            ar0[r] = alpha_s[4 * lg + r];
            ar1[r] = alpha_s[16 + 4 * lg + r];
        }
        __syncthreads();  // protects aliased SP + alpha_s before next iteration's writes
#pragma unroll
        for (int nf = 0; nf < 8; ++nf)
#pragma unroll
            for (int r = 0; r < 4; ++r) {
                acc[0][nf][r] *= ar0[r];
                acc[1][nf][r] *= ar1[r];
            }
        const f16* vp = Vg + (size_t)(128 * w + lr) * 2048 + key0 + 8 * lg;
#pragma unroll
        for (int nf = 0; nf < 8; ++nf) {
            f16x8 vb0 = *(const f16x8*)(vp + (size_t)nf * 16 * 2048);
            f16x8 vb1 = *(const f16x8*)(vp + (size_t)nf * 16 * 2048 + 32);
            acc[0][nf] = MFMA16(pa[0][0], vb0, acc[0][nf]);
            acc[1][nf] = MFMA16(pa[1][0], vb0, acc[1][nf]);
            acc[0][nf] = MFMA16(pa[0][1], vb1, acc[0][nf]);
            acc[1][nf] = MFMA16(pa[1][1], vb1, acc[1][nf]);
        }
    }
    if (g == 0) {
        lsum_s[srow8] = l_st;
        if (PART) {
            Ml[(size_t)bid * 64 + srow8 * 2] = m_st;
            Ml[(size_t)bid * 64 + srow8 * 2 + 1] = l_st;
        }
    }
    __syncthreads();
#pragma unroll
    for (int mf = 0; mf < 2; ++mf)
#pragma unroll
        for (int r = 0; r < 4; ++r) {
            int rr = 16 * mf + 4 * lg + r;
            float inv = 1.f / lsum_s[rr];
            if (PART) {
                f16* op = Opart + ((size_t)bid * 32 + rr) * 512 + 128 * w;
#pragma unroll
                for (int nf = 0; nf < 8; ++nf) op[16 * nf + lr] = (f16)(acc[mf][nf][r] * inv);
            } else {
                f16* op = AO + ((size_t)b * 2048 + q0 + rr) * 512 + 128 * w;
#pragma unroll
                for (int nf = 0; nf < 8; ++nf) op[16 * nf + lr] = (f16)(acc[mf][nf][r] * inv);
            }
        }
}

// ---------------- split-K combine ----------------
__global__ __launch_bounds__(256) void combine4(const f16* __restrict__ Opart, const float* __restrict__ Ml,
                                                f16* __restrict__ AO) {
    int gid = blockIdx.x * 256 + threadIdx.x;
    int row = gid >> 6, col0 = (gid & 63) * 8;
    int b = row >> 11, q = (row & 2047) >> 5, rr = row & 31;
    int bids[4];
    float m[4], ll[4];
#pragma unroll
    for (int s = 0; s < 4; ++s) {
        int t = q * 4 + s;
        bids[s] = (t >> 1) * 8 + 2 * b + (t & 1);
        m[s] = Ml[(size_t)bids[s] * 64 + rr * 2];
        ll[s] = Ml[(size_t)bids[s] * 64 + rr * 2 + 1];
    }
    float M = fmaxf(fmaxf(m[0], m[1]), fmaxf(m[2], m[3]));
    float c[4], W = 0.f;
#pragma unroll
    for (int s = 0; s < 4; ++s) {
        c[s] = __expf(m[s] - M) * ll[s];
        W += c[s];
    }
    float invW = 1.f / W;
    float av[8] = {};
#pragma unroll
    for (int s = 0; s < 4; ++s) {
        f16x8 v = *(const f16x8*)&Opart[((size_t)bids[s] * 32 + rr) * 512 + col0];
        float cs = c[s];
#pragma unroll
        for (int j = 0; j < 8; ++j) av[j] += cs * (float)v[j];
    }
    f16x8 o;
#pragma unroll
    for (int j = 0; j < 8; ++j) o[j] = (f16)(av[j] * invW);
    *(f16x8*)&AO[(size_t)row * 512 + col0] = o;
}

// ---------------- launch ----------------
extern "C" void kernel_launch(void* const* d_in, const int* in_sizes, int n_in,
                              void* d_out, int out_size, void* d_ws, size_t ws_size,
                              hipStream_t stream) {
    (void)in_sizes; (void)n_in; (void)out_size;
    const float* x = (const float*)d_in[0];
    const float* qkv_w = (const float*)d_in[1];
    const float* qkv_b = (const float*)d_in[2];
    const float* out_w = (const float*)d_in[3];
    const float* out_b = (const float*)d_in[4];
    char* ws = (char*)d_ws;
    f16* xh    = (f16*)(ws + 0);
    f16* wqkvh = (f16*)(ws + 8388608);
    f16* wouth = (f16*)(ws + 9961472);
    f16* Qb    = (f16*)(ws + 10485760);
    f16* Kb    = (f16*)(ws + 18874368);
    f16* Vt    = (f16*)(ws + 27262976);
    f16* AO    = (f16*)(ws + 35651584);
    f16* Opart = (f16*)(ws + 44040192);             // 1024*32*512*2 = 33,554,432
    float* Ml  = (float*)(ws + 44040192 + 33554432); // 1024*64*4 = 262,144
    const size_t NEED = 44040192ull + 33554432ull + 262144ull;

    cvt_f32_f16<<<4096, 256, 0, stream>>>(x, xh, 4194304);
    cvt_f32_f16<<<768, 256, 0, stream>>>(qkv_w, wqkvh, 786432);
    cvt_f32_f16<<<256, 256, 0, stream>>>(out_w, wouth, 262144);

    gemm_nt<0><<<dim3(128, 24), 256, 0, stream>>>(xh, wqkvh, qkv_b, nullptr, Qb, Kb, Vt);

    if (ws_size >= NEED) {
        flash_attn<4, true><<<1024, 256, 0, stream>>>(Qb, Kb, Vt, nullptr, Opart, Ml);
        combine4<<<2048, 256, 0, stream>>>(Opart, Ml, AO);
    } else {
        flash_attn<1, false><<<256, 256, 0, stream>>>(Qb, Kb, Vt, AO, nullptr, nullptr);
    }

    gemm_nt<1><<<dim3(128, 8), 256, 0, stream>>>(AO, wouth, out_b, (float*)d_out,
                                                 nullptr, nullptr, nullptr);
}